// Round 11
// baseline (493.974 us; speedup 1.0000x reference)
//
#include <hip/hip_runtime.h>
#include <stdint.h>

typedef _Float16 f16;
typedef _Float16 half8 __attribute__((ext_vector_type(8)));
typedef _Float16 half4v __attribute__((ext_vector_type(4)));
typedef float f32x4 __attribute__((ext_vector_type(4)));

#define MB (1024ull * 1024ull)
// ---- workspace layout (bytes) ----
#define WT_OFF 0ull            // 3 x 1024x1024 f16 = 6 MiB
#define QH_OFF (6ull * MB)     // 8192x1024 f16 = 16 MiB
#define KH_OFF (22ull * MB)    // 16 MiB
#define VT_OFF (38ull * MB)    // V^T [1024][8192] f16 = 16 MiB
#define PH_OFF (54ull * MB)    // P [8192][8192] f16 = 128 MiB
#define LP2_OFF (182ull * MB)  // lpart [128][8192] f32 = 4 MiB
#define LI_OFF (186ull * MB)   // linv [8192] f32

#define SB __builtin_amdgcn_sched_barrier(0)
#define BAR __builtin_amdgcn_s_barrier()
#define PR1 __builtin_amdgcn_s_setprio(1)
#define PR0 __builtin_amdgcn_s_setprio(0)
#define LGK0 asm volatile("s_waitcnt lgkmcnt(0)" ::: "memory")

__device__ __forceinline__ half8 cvt8(float4 a, float4 b) {
  half8 h;
  h[0] = (f16)a.x; h[1] = (f16)a.y; h[2] = (f16)a.z; h[3] = (f16)a.w;
  h[4] = (f16)b.x; h[5] = (f16)b.y; h[6] = (f16)b.z; h[7] = (f16)b.w;
  return h;
}

// async global->LDS, 16B/lane; LDS dst = wave-uniform byte offset (+lane*16 by HW)
__device__ __forceinline__ void gload16(const void* g, uint32_t lds_off) {
  __builtin_amdgcn_global_load_lds(
      (__attribute__((address_space(1))) void*)(uintptr_t)g,
      (__attribute__((address_space(3))) void*)lds_off, 16, 0, 0);
}

// ------------------------------------------------------------------
// K1: transpose-cast weights: Wt[z][dout][din] = (f16)W_z[din][dout]
// ------------------------------------------------------------------
__global__ void k_wt(const float* __restrict__ Wq, const float* __restrict__ Wk,
                     const float* __restrict__ Wv, f16* __restrict__ Wt) {
  __shared__ float tile[32][33];
  const int z = blockIdx.z;
  const float* W = (z == 0) ? Wq : ((z == 1) ? Wk : Wv);
  f16* dst = Wt + z * (1024 * 1024);
  const int tx = threadIdx.x, ty = threadIdx.y;
  const int r0 = blockIdx.y * 32, c0 = blockIdx.x * 32;
#pragma unroll
  for (int i = 0; i < 32; i += 8)
    tile[ty + i][tx] = W[(r0 + ty + i) * 1024 + c0 + tx];
  __syncthreads();
#pragma unroll
  for (int i = 0; i < 32; i += 8)
    dst[(c0 + ty + i) * 1024 + r0 + tx] = (f16)tile[tx][ty + i];
}

// ------------------------------------------------------------------
// K2: projection GEMM (fp32 X cast on the fly). Proven in R2; unchanged.
// ------------------------------------------------------------------
__launch_bounds__(256, 2)
__global__ void k_proj(const float* __restrict__ X, const f16* __restrict__ Wt,
                       f16* __restrict__ Qh, f16* __restrict__ Kh, f16* __restrict__ Vt) {
  __shared__ f16 As[2][128][40];
  __shared__ f16 Bs[2][128][40];
  const int z = blockIdx.z;
  const f16* Wz = Wt + z * (1024 * 1024);
  const int m0 = blockIdx.x * 128, n0 = blockIdx.y * 128;
  const int t = threadIdx.x;
  const int w = t >> 6, l = t & 63;
  const int wr = w >> 1, wc = w & 1;
  const int lr = l & 15, lk = (l >> 4) * 8;
  const int sr = t >> 1, sh = t & 1;

  const float* xsrc = X + (m0 + sr) * 1024 + sh * 16;
  const f16*   bsrc = Wz + (n0 + sr) * 1024 + sh * 16;

  f32x4 acc[4][4] = {};

  {
    float4 v0 = *(const float4*)(xsrc + 0);
    float4 v1 = *(const float4*)(xsrc + 4);
    float4 v2 = *(const float4*)(xsrc + 8);
    float4 v3 = *(const float4*)(xsrc + 12);
    *(half8*)(&As[0][sr][sh * 16 + 0]) = cvt8(v0, v1);
    *(half8*)(&As[0][sr][sh * 16 + 8]) = cvt8(v2, v3);
    *(half8*)(&Bs[0][sr][sh * 16 + 0]) = *(const half8*)(bsrc + 0);
    *(half8*)(&Bs[0][sr][sh * 16 + 8]) = *(const half8*)(bsrc + 8);
  }
  __syncthreads();

#pragma unroll 1
  for (int kt = 0; kt < 32; ++kt) {
    const int cur = kt & 1;
    float4 v0, v1, v2, v3;
    half8 b0, b1;
    if (kt < 31) {
      const float* xs = xsrc + (kt + 1) * 32;
      v0 = *(const float4*)(xs + 0);
      v1 = *(const float4*)(xs + 4);
      v2 = *(const float4*)(xs + 8);
      v3 = *(const float4*)(xs + 12);
      const f16* bs = bsrc + (kt + 1) * 32;
      b0 = *(const half8*)(bs + 0);
      b1 = *(const half8*)(bs + 8);
    }
    half8 af[4], bf[4];
#pragma unroll
    for (int mi = 0; mi < 4; ++mi)
      af[mi] = *(const half8*)(&As[cur][wr * 64 + mi * 16 + lr][lk]);
#pragma unroll
    for (int ni = 0; ni < 4; ++ni)
      bf[ni] = *(const half8*)(&Bs[cur][wc * 64 + ni * 16 + lr][lk]);
#pragma unroll
    for (int mi = 0; mi < 4; ++mi)
#pragma unroll
      for (int ni = 0; ni < 4; ++ni)
        acc[mi][ni] = __builtin_amdgcn_mfma_f32_16x16x32_f16(af[mi], bf[ni], acc[mi][ni], 0, 0, 0);
    if (kt < 31) {
      *(half8*)(&As[cur ^ 1][sr][sh * 16 + 0]) = cvt8(v0, v1);
      *(half8*)(&As[cur ^ 1][sr][sh * 16 + 8]) = cvt8(v2, v3);
      *(half8*)(&Bs[cur ^ 1][sr][sh * 16 + 0]) = b0;
      *(half8*)(&Bs[cur ^ 1][sr][sh * 16 + 8]) = b1;
    }
    __syncthreads();
  }

  if (z < 2) {
    f16* dst = (z == 0) ? Qh : Kh;
#pragma unroll
    for (int mi = 0; mi < 4; ++mi)
#pragma unroll
      for (int ni = 0; ni < 4; ++ni) {
        const int row = m0 + wr * 64 + mi * 16 + (l >> 4) * 4;
        const int col = n0 + wc * 64 + ni * 16 + lr;
#pragma unroll
        for (int r = 0; r < 4; ++r)
          dst[(row + r) * 1024 + col] = (f16)acc[mi][ni][r];
      }
  } else {
#pragma unroll
    for (int mi = 0; mi < 4; ++mi)
#pragma unroll
      for (int ni = 0; ni < 4; ++ni) {
        const int row = m0 + wr * 64 + mi * 16 + (l >> 4) * 4;
        const int col = n0 + wc * 64 + ni * 16 + lr;
        half4v v = {(f16)acc[mi][ni][0], (f16)acc[mi][ni][1],
                    (f16)acc[mi][ni][2], (f16)acc[mi][ni][3]};
        *(half4v*)(&Vt[col * 8192 + row]) = v;
      }
  }
}

// ------------------------------------------------------------------
// K3: S = Q@K^T, P = exp(S/32) -> Ph f16; row-sum partials -> lpart.
// R8 kernel byte-exact (measured 159 us, MfmaUtil 39.5%, FETCH 107 MB):
// 128x128 tile, 4 waves 2x2, 32KB LDS (~3 blocks/CU), L2-resident 4x4
// supertile per XCD. R9/R10 showed both wave-tile directions are worse.
// ------------------------------------------------------------------
__launch_bounds__(256, 2)
__global__ void k_sexp(const f16* __restrict__ Qh, const f16* __restrict__ Kh,
                       f16* __restrict__ Ph, float* __restrict__ lpart) {
  __shared__ __align__(128) char smem[32768];  // A[128][64] | B[128][64] f16
  const int t = threadIdx.x;
  const int w = t >> 6, l = t & 63;
  const int wr = w >> 1, wc = w & 1;
  const int lr = l & 15, g = l >> 4;
  const int bid = blockIdx.x;
  // supertile mapping: xcd-resident K working set (8 n-panels = 2 MB / L2)
  const int xcd = bid & 7, gid = bid >> 3;
  const int st = (gid >> 4) * 8 + xcd;            // supertile id, [0,256)
  const int idx = gid & 15;                       // tile within 4x4 supertile
  const int mt = ((st >> 4) << 2) + (idx >> 2);   // [0,64)
  const int nt = ((st & 15) << 2) + (idx & 3);    // [0,64)
  const int m0 = mt << 7, n0 = nt << 7;

  const uint32_t lds0 = (uint32_t)(uintptr_t)(void*)smem;
  f32x4 acc[4][4] = {};

#pragma unroll 1
  for (int kt = 0; kt < 16; ++kt) {
#pragma unroll
    for (int i = 0; i < 4; ++i) {
      const int r = ((i << 8) + t) >> 3;
      const int sl = (t & 7) ^ (r & 7);
      gload16(Qh + (size_t)(m0 + r) * 1024 + (kt << 6) + (sl << 3),
              lds0 + (i << 12) + (w << 10));
      gload16(Kh + (size_t)(n0 + r) * 1024 + (kt << 6) + (sl << 3),
              lds0 + 16384 + (i << 12) + (w << 10));
    }
    __syncthreads();
#pragma unroll
    for (int ks = 0; ks < 2; ++ks) {
      half8 af[4], bf[4];
#pragma unroll
      for (int mi = 0; mi < 4; ++mi) {
        const int row = wr * 64 + mi * 16 + lr;
        const int sp = ((ks << 2) + g) ^ (row & 7);
        af[mi] = *(const half8*)(smem + row * 128 + sp * 16);
      }
#pragma unroll
      for (int ni = 0; ni < 4; ++ni) {
        const int row = wc * 64 + ni * 16 + lr;
        const int sp = ((ks << 2) + g) ^ (row & 7);
        bf[ni] = *(const half8*)(smem + 16384 + row * 128 + sp * 16);
      }
#pragma unroll
      for (int mi = 0; mi < 4; ++mi)
#pragma unroll
        for (int ni = 0; ni < 4; ++ni)
          acc[mi][ni] = __builtin_amdgcn_mfma_f32_16x16x32_f16(af[mi], bf[ni], acc[mi][ni], 0, 0, 0);
    }
    __syncthreads();
  }

  // epilogue: p = exp(acc/32) = 2^(acc*log2e/32), row partials, P tile via LDS
  float rs[4][4] = {};
#pragma unroll
  for (int mi = 0; mi < 4; ++mi)
#pragma unroll
    for (int ni = 0; ni < 4; ++ni)
#pragma unroll
      for (int r = 0; r < 4; ++r) {
        const float p = exp2f(acc[mi][ni][r] * 0.045084222f);
        rs[mi][r] += p;
        const int row = wr * 64 + mi * 16 + g * 4 + r;
        const int col = wc * 64 + ni * 16 + lr;
        *(f16*)(smem + row * 256 + ((col * 2) ^ (((row >> 2) & 7) << 4))) = (f16)p;
      }
#pragma unroll
  for (int mi = 0; mi < 4; ++mi)
#pragma unroll
    for (int r = 0; r < 4; ++r) {
      float v = rs[mi][r];
      v += __shfl_xor(v, 1);
      v += __shfl_xor(v, 2);
      v += __shfl_xor(v, 4);
      v += __shfl_xor(v, 8);
      rs[mi][r] = v;
    }
  if (lr == 0) {
#pragma unroll
    for (int mi = 0; mi < 4; ++mi)
#pragma unroll
      for (int r = 0; r < 4; ++r)
        lpart[(size_t)(nt * 2 + wc) * 8192 + m0 + wr * 64 + mi * 16 + g * 4 + r] = rs[mi][r];
  }
  __syncthreads();
#pragma unroll
  for (int j = 0; j < 8; ++j) {
    const int row = j * 16 + (t >> 4);
    const int c16 = t & 15;
    *(int4*)(Ph + (size_t)(m0 + row) * 8192 + n0 + c16 * 8) =
        *(const int4*)(smem + row * 256 + ((c16 * 16) ^ (((row >> 2) & 7) << 4)));
  }
}

// ------------------------------------------------------------------
// K5 (pv): P=2 pipeline GEMM, fenced schedule + counted vmcnt.
// R11 change (one variable): L2-resident Vt mapping — each XCD owns ONE
// dout-panel of Vt (128 x 8192 f16 = 2 MB, resident in its 4 MB L2;
// 8 panels == 8 XCDs exactly), P rows stream once via shared L3 (128 MB
// < 256 MB). Old mapping gave each XCD all 8 panels (16 MB working set,
// thrash). Predict pv FETCH ~600 -> ~150 MB.
// ------------------------------------------------------------------
template <int WN, int BN, int NK, int LDA, int LDB>
__launch_bounds__(512, 2)
__global__ void k_g8(const f16* __restrict__ Ag, const f16* __restrict__ Bg,
                     const float* __restrict__ linv, float* __restrict__ outp) {
  constexpr int WM = 8 / WN;
  constexpr int WTM = 256 / WM;
  constexpr int NRM = WTM / 16;
  constexpr int BKS = BN * 64;
  constexpr int NLB = BN / 128;
  constexpr int BBASE = 65536;

  __shared__ __align__(128) char smem[BBASE + 4 * BKS];

  const int t = threadIdx.x;
  const int w = t >> 6, l = t & 63;
  const int lr = l & 15, g = l >> 4;
  const int wr = w / WN, wc = w % WN;
  const int bid = blockIdx.x;
  const int ntl = bid & 7;        // XCD-resident Vt panel (1 panel per XCD)
  const int mt = bid >> 3;        // P m-tile streams across L3
  const int m0 = mt * 256, n0 = ntl * BN;

  const uint32_t lds0 = (uint32_t)(uintptr_t)(void*)smem;
  const int lq = l >> 2, ls = l & 3;
  const int sw = (ls ^ ((lq >> 1) & 3)) << 3;
  const int rdsw = (g ^ ((lr >> 1) & 3)) << 4;

  auto stA = [&](int kS, int ks, int b) {
#pragma unroll
    for (int j = 0; j < 2; ++j) {
      const int rl = w * 32 + j * 16 + lq;
      gload16(Ag + (size_t)(m0 + rl) * LDA + kS * 64 + ks * 32 + sw,
              lds0 + b * 32768 + ks * 16384 + (w * 2 + j) * 1024);
    }
  };
  auto stB = [&](int kS, int ks, int b) {
#pragma unroll
    for (int j = 0; j < NLB; ++j) {
      const int rl = w * (16 * NLB) + j * 16 + lq;
      gload16(Bg + (size_t)(n0 + rl) * LDB + kS * 64 + ks * 32 + sw,
              lds0 + BBASE + b * (2 * BKS) + ks * BKS + (w * NLB + j) * 1024);
    }
  };

  f32x4 acc[NRM][4] = {};

  stA(0, 0, 0); stB(0, 0, 0);
  stA(0, 1, 0); stB(0, 1, 0);
  stA(1, 0, 1); stB(1, 0, 1);
  asm volatile("s_waitcnt vmcnt(6)" ::: "memory");  // retire (0,ks0); keep 2 stages
  SB;
  BAR;

#pragma unroll 1
  for (int kt = 0; kt < NK; ++kt) {
    const int b = kt & 1;
    const int k1 = (kt + 1 < NK) ? kt + 1 : kt;
    const int k2 = (kt + 2 < NK) ? kt + 2 : kt;
#pragma unroll
    for (int ks = 0; ks < 2; ++ks) {
      half8 af[NRM], bf[4];
#pragma unroll
      for (int mi = 0; mi < NRM; ++mi)
        af[mi] = *(const half8*)(smem + b * 32768 + ks * 16384 +
                                 (wr * WTM + mi * 16 + lr) * 64 + rdsw);
#pragma unroll
      for (int ni = 0; ni < 4; ++ni)
        bf[ni] = *(const half8*)(smem + BBASE + b * (2 * BKS) + ks * BKS +
                                 (wc * 64 + ni * 16 + lr) * 64 + rdsw);
      if (ks == 0) { stA(k1, 1, b ^ 1); stB(k1, 1, b ^ 1); }
      else         { stA(k2, 0, b);     stB(k2, 0, b); }
      asm volatile("s_waitcnt vmcnt(6)" ::: "memory");  // retire 3-phases-old stage
      SB; BAR; LGK0; SB; PR1;
#pragma unroll
      for (int mi = 0; mi < NRM; ++mi)
#pragma unroll
        for (int ni = 0; ni < 4; ++ni)
          acc[mi][ni] = __builtin_amdgcn_mfma_f32_16x16x32_f16(af[mi], bf[ni], acc[mi][ni], 0, 0, 0);
      PR0; SB; BAR;
    }
  }
  asm volatile("s_waitcnt vmcnt(0)" ::: "memory");
  BAR;

#pragma unroll
  for (int mi = 0; mi < NRM; ++mi) {
#pragma unroll
    for (int r = 0; r < 4; ++r) {
      const int rowg = m0 + wr * WTM + mi * 16 + g * 4 + r;
      const float iv = linv[rowg];
#pragma unroll
      for (int ni = 0; ni < 4; ++ni)
        outp[(size_t)rowg * 1024 + n0 + wc * 64 + ni * 16 + lr] = acc[mi][ni][r] * iv;
    }
  }
}

// ------------------------------------------------------------------
// K4: reduce 128 row-sum partials -> inverse row sums
// ------------------------------------------------------------------
__global__ void k_lred(const float* __restrict__ lpart, float* __restrict__ linv) {
  const int r = blockIdx.x * 256 + threadIdx.x;
  float s = 0.f;
#pragma unroll
  for (int i = 0; i < 128; ++i) s += lpart[(size_t)i * 8192 + r];
  linv[r] = 1.0f / s;
}

// ------------------------------------------------------------------
extern "C" void kernel_launch(void* const* d_in, const int* in_sizes, int n_in,
                              void* d_out, int out_size, void* d_ws, size_t ws_size,
                              hipStream_t stream) {
  (void)in_sizes; (void)n_in; (void)out_size; (void)ws_size;
  const float* X  = (const float*)d_in[0];
  const float* Wq = (const float*)d_in[1];
  const float* Wk = (const float*)d_in[2];
  const float* Wv = (const float*)d_in[3];
  char* ws = (char*)d_ws;
  f16* Wt = (f16*)(ws + WT_OFF);
  f16* Qh = (f16*)(ws + QH_OFF);
  f16* Kh = (f16*)(ws + KH_OFF);
  f16* Vt = (f16*)(ws + VT_OFF);
  f16* Ph = (f16*)(ws + PH_OFF);
  float* lpart = (float*)(ws + LP2_OFF);
  float* linv  = (float*)(ws + LI_OFF);
  float* out = (float*)d_out;

  k_wt  <<<dim3(32, 32, 3), dim3(32, 8), 0, stream>>>(Wq, Wk, Wv, Wt);
  k_proj<<<dim3(64, 8, 3),  dim3(256),   0, stream>>>(X, Wt, Qh, Kh, Vt);
  // S = Q@K^T -> P = exp(S/32): M=N=8192, K=1024; 64x64 tiles of 128^2
  k_sexp<<<dim3(4096), dim3(256), 0, stream>>>(Qh, Kh, Ph, lpart);
  k_lred<<<dim3(32), dim3(256), 0, stream>>>(lpart, linv);
  // out = (P@V) * linv: M=8192, N=1024, K=8192; 32x8 tiles of 256x128
  k_g8<2, 128, 128, 8192, 8192><<<dim3(256), dim3(512), 0, stream>>>(
      Ph, Vt, linv, out);
}

// Round 12
// 410.053 us; speedup vs baseline: 1.2047x; 1.2047x over previous
//
#include <hip/hip_runtime.h>
#include <stdint.h>

typedef _Float16 f16;
typedef _Float16 half8 __attribute__((ext_vector_type(8)));
typedef _Float16 half4v __attribute__((ext_vector_type(4)));
typedef float f32x4 __attribute__((ext_vector_type(4)));

#define MB (1024ull * 1024ull)
// ---- workspace layout (bytes) ----
#define WT_OFF 0ull            // 3 x 1024x1024 f16 = 6 MiB
#define QH_OFF (6ull * MB)     // 8192x1024 f16 = 16 MiB
#define KH_OFF (22ull * MB)    // 16 MiB
#define VT_OFF (38ull * MB)    // V^T [1024][8192] f16 = 16 MiB
#define PH_OFF (54ull * MB)    // P [8192][8192] f16 = 128 MiB
#define LP2_OFF (182ull * MB)  // lpart [128][8192] f32 = 4 MiB
#define LI_OFF (186ull * MB)   // linv [8192] f32

#define SB __builtin_amdgcn_sched_barrier(0)
#define BAR __builtin_amdgcn_s_barrier()
#define PR1 __builtin_amdgcn_s_setprio(1)
#define PR0 __builtin_amdgcn_s_setprio(0)
#define LGK0 asm volatile("s_waitcnt lgkmcnt(0)" ::: "memory")

__device__ __forceinline__ half8 cvt8(float4 a, float4 b) {
  half8 h;
  h[0] = (f16)a.x; h[1] = (f16)a.y; h[2] = (f16)a.z; h[3] = (f16)a.w;
  h[4] = (f16)b.x; h[5] = (f16)b.y; h[6] = (f16)b.z; h[7] = (f16)b.w;
  return h;
}

// async global->LDS, 16B/lane; LDS dst = wave-uniform byte offset (+lane*16 by HW)
__device__ __forceinline__ void gload16(const void* g, uint32_t lds_off) {
  __builtin_amdgcn_global_load_lds(
      (__attribute__((address_space(1))) void*)(uintptr_t)g,
      (__attribute__((address_space(3))) void*)lds_off, 16, 0, 0);
}

// ------------------------------------------------------------------
// K1: transpose-cast weights: Wt[z][dout][din] = (f16)W_z[din][dout]
// ------------------------------------------------------------------
__global__ void k_wt(const float* __restrict__ Wq, const float* __restrict__ Wk,
                     const float* __restrict__ Wv, f16* __restrict__ Wt) {
  __shared__ float tile[32][33];
  const int z = blockIdx.z;
  const float* W = (z == 0) ? Wq : ((z == 1) ? Wk : Wv);
  f16* dst = Wt + z * (1024 * 1024);
  const int tx = threadIdx.x, ty = threadIdx.y;
  const int r0 = blockIdx.y * 32, c0 = blockIdx.x * 32;
#pragma unroll
  for (int i = 0; i < 32; i += 8)
    tile[ty + i][tx] = W[(r0 + ty + i) * 1024 + c0 + tx];
  __syncthreads();
#pragma unroll
  for (int i = 0; i < 32; i += 8)
    dst[(c0 + ty + i) * 1024 + r0 + tx] = (f16)tile[tx][ty + i];
}

// ------------------------------------------------------------------
// K2: projection GEMM (fp32 X cast on the fly). Proven in R2; unchanged.
// ------------------------------------------------------------------
__launch_bounds__(256, 2)
__global__ void k_proj(const float* __restrict__ X, const f16* __restrict__ Wt,
                       f16* __restrict__ Qh, f16* __restrict__ Kh, f16* __restrict__ Vt) {
  __shared__ f16 As[2][128][40];
  __shared__ f16 Bs[2][128][40];
  const int z = blockIdx.z;
  const f16* Wz = Wt + z * (1024 * 1024);
  const int m0 = blockIdx.x * 128, n0 = blockIdx.y * 128;
  const int t = threadIdx.x;
  const int w = t >> 6, l = t & 63;
  const int wr = w >> 1, wc = w & 1;
  const int lr = l & 15, lk = (l >> 4) * 8;
  const int sr = t >> 1, sh = t & 1;

  const float* xsrc = X + (m0 + sr) * 1024 + sh * 16;
  const f16*   bsrc = Wz + (n0 + sr) * 1024 + sh * 16;

  f32x4 acc[4][4] = {};

  {
    float4 v0 = *(const float4*)(xsrc + 0);
    float4 v1 = *(const float4*)(xsrc + 4);
    float4 v2 = *(const float4*)(xsrc + 8);
    float4 v3 = *(const float4*)(xsrc + 12);
    *(half8*)(&As[0][sr][sh * 16 + 0]) = cvt8(v0, v1);
    *(half8*)(&As[0][sr][sh * 16 + 8]) = cvt8(v2, v3);
    *(half8*)(&Bs[0][sr][sh * 16 + 0]) = *(const half8*)(bsrc + 0);
    *(half8*)(&Bs[0][sr][sh * 16 + 8]) = *(const half8*)(bsrc + 8);
  }
  __syncthreads();

#pragma unroll 1
  for (int kt = 0; kt < 32; ++kt) {
    const int cur = kt & 1;
    float4 v0, v1, v2, v3;
    half8 b0, b1;
    if (kt < 31) {
      const float* xs = xsrc + (kt + 1) * 32;
      v0 = *(const float4*)(xs + 0);
      v1 = *(const float4*)(xs + 4);
      v2 = *(const float4*)(xs + 8);
      v3 = *(const float4*)(xs + 12);
      const f16* bs = bsrc + (kt + 1) * 32;
      b0 = *(const half8*)(bs + 0);
      b1 = *(const half8*)(bs + 8);
    }
    half8 af[4], bf[4];
#pragma unroll
    for (int mi = 0; mi < 4; ++mi)
      af[mi] = *(const half8*)(&As[cur][wr * 64 + mi * 16 + lr][lk]);
#pragma unroll
    for (int ni = 0; ni < 4; ++ni)
      bf[ni] = *(const half8*)(&Bs[cur][wc * 64 + ni * 16 + lr][lk]);
#pragma unroll
    for (int mi = 0; mi < 4; ++mi)
#pragma unroll
      for (int ni = 0; ni < 4; ++ni)
        acc[mi][ni] = __builtin_amdgcn_mfma_f32_16x16x32_f16(af[mi], bf[ni], acc[mi][ni], 0, 0, 0);
    if (kt < 31) {
      *(half8*)(&As[cur ^ 1][sr][sh * 16 + 0]) = cvt8(v0, v1);
      *(half8*)(&As[cur ^ 1][sr][sh * 16 + 8]) = cvt8(v2, v3);
      *(half8*)(&Bs[cur ^ 1][sr][sh * 16 + 0]) = b0;
      *(half8*)(&Bs[cur ^ 1][sr][sh * 16 + 8]) = b1;
    }
    __syncthreads();
  }

  if (z < 2) {
    f16* dst = (z == 0) ? Qh : Kh;
#pragma unroll
    for (int mi = 0; mi < 4; ++mi)
#pragma unroll
      for (int ni = 0; ni < 4; ++ni) {
        const int row = m0 + wr * 64 + mi * 16 + (l >> 4) * 4;
        const int col = n0 + wc * 64 + ni * 16 + lr;
#pragma unroll
        for (int r = 0; r < 4; ++r)
          dst[(row + r) * 1024 + col] = (f16)acc[mi][ni][r];
      }
  } else {
#pragma unroll
    for (int mi = 0; mi < 4; ++mi)
#pragma unroll
      for (int ni = 0; ni < 4; ++ni) {
        const int row = m0 + wr * 64 + mi * 16 + (l >> 4) * 4;
        const int col = n0 + wc * 64 + ni * 16 + lr;
        half4v v = {(f16)acc[mi][ni][0], (f16)acc[mi][ni][1],
                    (f16)acc[mi][ni][2], (f16)acc[mi][ni][3]};
        *(half4v*)(&Vt[col * 8192 + row]) = v;
      }
  }
}

// ------------------------------------------------------------------
// K3: S = Q@K^T, P = exp(S/32) -> Ph f16; row-sum partials -> lpart.
// R8 kernel byte-exact (measured 159 us, MfmaUtil 39.5%, FETCH 107 MB):
// 128x128 tile, 4 waves 2x2, 32KB LDS (~3 blocks/CU), L2-resident 4x4
// supertile per XCD. R9/R10 showed both wave-tile directions are worse.
// ------------------------------------------------------------------
__launch_bounds__(256, 2)
__global__ void k_sexp(const f16* __restrict__ Qh, const f16* __restrict__ Kh,
                       f16* __restrict__ Ph, float* __restrict__ lpart) {
  __shared__ __align__(128) char smem[32768];  // A[128][64] | B[128][64] f16
  const int t = threadIdx.x;
  const int w = t >> 6, l = t & 63;
  const int wr = w >> 1, wc = w & 1;
  const int lr = l & 15, g = l >> 4;
  const int bid = blockIdx.x;
  // supertile mapping: xcd-resident K working set (8 n-panels = 2 MB / L2)
  const int xcd = bid & 7, gid = bid >> 3;
  const int st = (gid >> 4) * 8 + xcd;            // supertile id, [0,256)
  const int idx = gid & 15;                       // tile within 4x4 supertile
  const int mt = ((st >> 4) << 2) + (idx >> 2);   // [0,64)
  const int nt = ((st & 15) << 2) + (idx & 3);    // [0,64)
  const int m0 = mt << 7, n0 = nt << 7;

  const uint32_t lds0 = (uint32_t)(uintptr_t)(void*)smem;
  f32x4 acc[4][4] = {};

#pragma unroll 1
  for (int kt = 0; kt < 16; ++kt) {
#pragma unroll
    for (int i = 0; i < 4; ++i) {
      const int r = ((i << 8) + t) >> 3;
      const int sl = (t & 7) ^ (r & 7);
      gload16(Qh + (size_t)(m0 + r) * 1024 + (kt << 6) + (sl << 3),
              lds0 + (i << 12) + (w << 10));
      gload16(Kh + (size_t)(n0 + r) * 1024 + (kt << 6) + (sl << 3),
              lds0 + 16384 + (i << 12) + (w << 10));
    }
    __syncthreads();
#pragma unroll
    for (int ks = 0; ks < 2; ++ks) {
      half8 af[4], bf[4];
#pragma unroll
      for (int mi = 0; mi < 4; ++mi) {
        const int row = wr * 64 + mi * 16 + lr;
        const int sp = ((ks << 2) + g) ^ (row & 7);
        af[mi] = *(const half8*)(smem + row * 128 + sp * 16);
      }
#pragma unroll
      for (int ni = 0; ni < 4; ++ni) {
        const int row = wc * 64 + ni * 16 + lr;
        const int sp = ((ks << 2) + g) ^ (row & 7);
        bf[ni] = *(const half8*)(smem + 16384 + row * 128 + sp * 16);
      }
#pragma unroll
      for (int mi = 0; mi < 4; ++mi)
#pragma unroll
        for (int ni = 0; ni < 4; ++ni)
          acc[mi][ni] = __builtin_amdgcn_mfma_f32_16x16x32_f16(af[mi], bf[ni], acc[mi][ni], 0, 0, 0);
    }
    __syncthreads();
  }

  // epilogue: p = exp(acc/32) = 2^(acc*log2e/32), row partials, P tile via LDS
  float rs[4][4] = {};
#pragma unroll
  for (int mi = 0; mi < 4; ++mi)
#pragma unroll
    for (int ni = 0; ni < 4; ++ni)
#pragma unroll
      for (int r = 0; r < 4; ++r) {
        const float p = exp2f(acc[mi][ni][r] * 0.045084222f);
        rs[mi][r] += p;
        const int row = wr * 64 + mi * 16 + g * 4 + r;
        const int col = wc * 64 + ni * 16 + lr;
        *(f16*)(smem + row * 256 + ((col * 2) ^ (((row >> 2) & 7) << 4))) = (f16)p;
      }
#pragma unroll
  for (int mi = 0; mi < 4; ++mi)
#pragma unroll
    for (int r = 0; r < 4; ++r) {
      float v = rs[mi][r];
      v += __shfl_xor(v, 1);
      v += __shfl_xor(v, 2);
      v += __shfl_xor(v, 4);
      v += __shfl_xor(v, 8);
      rs[mi][r] = v;
    }
  if (lr == 0) {
#pragma unroll
    for (int mi = 0; mi < 4; ++mi)
#pragma unroll
      for (int r = 0; r < 4; ++r)
        lpart[(size_t)(nt * 2 + wc) * 8192 + m0 + wr * 64 + mi * 16 + g * 4 + r] = rs[mi][r];
  }
  __syncthreads();
#pragma unroll
  for (int j = 0; j < 8; ++j) {
    const int row = j * 16 + (t >> 4);
    const int c16 = t & 15;
    *(int4*)(Ph + (size_t)(m0 + row) * 8192 + n0 + c16 * 8) =
        *(const int4*)(smem + row * 256 + ((c16 * 16) ^ (((row >> 2) & 7) << 4)));
  }
}

// ------------------------------------------------------------------
// K5 (pv): P=2 pipeline GEMM, fenced schedule + counted vmcnt.
// R12: mapping REVERTED to R10's (R11's Vt-resident remap destroyed
// intra-XCD P reuse: each XCD streamed all 128 MB of P -> FETCH 716 MB,
// 245 us). R10 mapping: XCD x owns mt in [4x, 4x+4) x all 8 ntl
// concurrently -> each P row fetched once into L2, reused 8x; Vt (16 MB)
// is L3-resident for free.
// ------------------------------------------------------------------
template <int WN, int BN, int NK, int LDA, int LDB>
__launch_bounds__(512, 2)
__global__ void k_g8(const f16* __restrict__ Ag, const f16* __restrict__ Bg,
                     const float* __restrict__ linv, float* __restrict__ outp) {
  constexpr int WM = 8 / WN;
  constexpr int WTM = 256 / WM;
  constexpr int NRM = WTM / 16;
  constexpr int BKS = BN * 64;
  constexpr int NLB = BN / 128;
  constexpr int BBASE = 65536;
  constexpr int NTN = 1024 / BN;
  constexpr int CPX = (32 * NTN) / 8;

  __shared__ __align__(128) char smem[BBASE + 4 * BKS];

  const int t = threadIdx.x;
  const int w = t >> 6, l = t & 63;
  const int lr = l & 15, g = l >> 4;
  const int wr = w / WN, wc = w % WN;
  const int bid = blockIdx.x;
  const int swz = (bid & 7) * CPX + (bid >> 3);
  const int mt = swz / NTN, ntl = swz % NTN;
  const int m0 = mt * 256, n0 = ntl * BN;

  const uint32_t lds0 = (uint32_t)(uintptr_t)(void*)smem;
  const int lq = l >> 2, ls = l & 3;
  const int sw = (ls ^ ((lq >> 1) & 3)) << 3;
  const int rdsw = (g ^ ((lr >> 1) & 3)) << 4;

  auto stA = [&](int kS, int ks, int b) {
#pragma unroll
    for (int j = 0; j < 2; ++j) {
      const int rl = w * 32 + j * 16 + lq;
      gload16(Ag + (size_t)(m0 + rl) * LDA + kS * 64 + ks * 32 + sw,
              lds0 + b * 32768 + ks * 16384 + (w * 2 + j) * 1024);
    }
  };
  auto stB = [&](int kS, int ks, int b) {
#pragma unroll
    for (int j = 0; j < NLB; ++j) {
      const int rl = w * (16 * NLB) + j * 16 + lq;
      gload16(Bg + (size_t)(n0 + rl) * LDB + kS * 64 + ks * 32 + sw,
              lds0 + BBASE + b * (2 * BKS) + ks * BKS + (w * NLB + j) * 1024);
    }
  };

  f32x4 acc[NRM][4] = {};

  stA(0, 0, 0); stB(0, 0, 0);
  stA(0, 1, 0); stB(0, 1, 0);
  stA(1, 0, 1); stB(1, 0, 1);
  asm volatile("s_waitcnt vmcnt(6)" ::: "memory");  // retire (0,ks0); keep 2 stages
  SB;
  BAR;

#pragma unroll 1
  for (int kt = 0; kt < NK; ++kt) {
    const int b = kt & 1;
    const int k1 = (kt + 1 < NK) ? kt + 1 : kt;
    const int k2 = (kt + 2 < NK) ? kt + 2 : kt;
#pragma unroll
    for (int ks = 0; ks < 2; ++ks) {
      half8 af[NRM], bf[4];
#pragma unroll
      for (int mi = 0; mi < NRM; ++mi)
        af[mi] = *(const half8*)(smem + b * 32768 + ks * 16384 +
                                 (wr * WTM + mi * 16 + lr) * 64 + rdsw);
#pragma unroll
      for (int ni = 0; ni < 4; ++ni)
        bf[ni] = *(const half8*)(smem + BBASE + b * (2 * BKS) + ks * BKS +
                                 (wc * 64 + ni * 16 + lr) * 64 + rdsw);
      if (ks == 0) { stA(k1, 1, b ^ 1); stB(k1, 1, b ^ 1); }
      else         { stA(k2, 0, b);     stB(k2, 0, b); }
      asm volatile("s_waitcnt vmcnt(6)" ::: "memory");  // retire 3-phases-old stage
      SB; BAR; LGK0; SB; PR1;
#pragma unroll
      for (int mi = 0; mi < NRM; ++mi)
#pragma unroll
        for (int ni = 0; ni < 4; ++ni)
          acc[mi][ni] = __builtin_amdgcn_mfma_f32_16x16x32_f16(af[mi], bf[ni], acc[mi][ni], 0, 0, 0);
      PR0; SB; BAR;
    }
  }
  asm volatile("s_waitcnt vmcnt(0)" ::: "memory");
  BAR;

#pragma unroll
  for (int mi = 0; mi < NRM; ++mi) {
#pragma unroll
    for (int r = 0; r < 4; ++r) {
      const int rowg = m0 + wr * WTM + mi * 16 + g * 4 + r;
      const float iv = linv[rowg];
#pragma unroll
      for (int ni = 0; ni < 4; ++ni)
        outp[(size_t)rowg * 1024 + n0 + wc * 64 + ni * 16 + lr] = acc[mi][ni][r] * iv;
    }
  }
}

// ------------------------------------------------------------------
// K4: reduce 128 row-sum partials -> inverse row sums
// ------------------------------------------------------------------
__global__ void k_lred(const float* __restrict__ lpart, float* __restrict__ linv) {
  const int r = blockIdx.x * 256 + threadIdx.x;
  float s = 0.f;
#pragma unroll
  for (int i = 0; i < 128; ++i) s += lpart[(size_t)i * 8192 + r];
  linv[r] = 1.0f / s;
}

// ------------------------------------------------------------------
extern "C" void kernel_launch(void* const* d_in, const int* in_sizes, int n_in,
                              void* d_out, int out_size, void* d_ws, size_t ws_size,
                              hipStream_t stream) {
  (void)in_sizes; (void)n_in; (void)out_size; (void)ws_size;
  const float* X  = (const float*)d_in[0];
  const float* Wq = (const float*)d_in[1];
  const float* Wk = (const float*)d_in[2];
  const float* Wv = (const float*)d_in[3];
  char* ws = (char*)d_ws;
  f16* Wt = (f16*)(ws + WT_OFF);
  f16* Qh = (f16*)(ws + QH_OFF);
  f16* Kh = (f16*)(ws + KH_OFF);
  f16* Vt = (f16*)(ws + VT_OFF);
  f16* Ph = (f16*)(ws + PH_OFF);
  float* lpart = (float*)(ws + LP2_OFF);
  float* linv  = (float*)(ws + LI_OFF);
  float* out = (float*)d_out;

  k_wt  <<<dim3(32, 32, 3), dim3(32, 8), 0, stream>>>(Wq, Wk, Wv, Wt);
  k_proj<<<dim3(64, 8, 3),  dim3(256),   0, stream>>>(X, Wt, Qh, Kh, Vt);
  // S = Q@K^T -> P = exp(S/32): M=N=8192, K=1024; 64x64 tiles of 128^2
  k_sexp<<<dim3(4096), dim3(256), 0, stream>>>(Qh, Kh, Ph, lpart);
  k_lred<<<dim3(32), dim3(256), 0, stream>>>(lpart, linv);
  // out = (P@V) * linv: M=8192, N=1024, K=8192; 32x8 tiles of 256x128
  k_g8<2, 128, 128, 8192, 8192><<<dim3(256), dim3(512), 0, stream>>>(
      Ph, Vt, linv, out);
}